// Round 9
// baseline (490.068 us; speedup 1.0000x reference)
//
#include <hip/hip_runtime.h>
#include <hip/hip_bf16.h>
#include <stdint.h>

#define N 8192
#define E 256
#define NUM_CLASSES 100
#define MARGIN 0.1f
#define EPS 1e-4f

#define BT 128                      // Gram tile dim
#define MT (N / BT)                 // 64 tile-rows
#define NTILES (MT * (MT + 1) / 2)  // 2080 upper-tri tiles
#define SL (2 * MT)                 // 128 partial slices (2 per tile index)
#define EB 256                      // fp8 row = 256 B
#define FINB 32                     // finisher blocks (ticket tail)

typedef __attribute__((ext_vector_type(4))) float floatx4;
typedef __attribute__((ext_vector_type(2))) long longx2;
typedef const __attribute__((address_space(1))) void* gptr_t;
typedef __attribute__((address_space(3))) void* sptr_t;

struct Ctrl { double Ssum; int c1, c2; };  // zeroed by prep block 0

// 16-lane butterfly sum on the VALU via DPP (no LDS-pipe usage).
__device__ __forceinline__ float dpp_sum16(float v) {
  v += __int_as_float(__builtin_amdgcn_update_dpp(0, __float_as_int(v), 0xB1, 0xF, 0xF, true));
  v += __int_as_float(__builtin_amdgcn_update_dpp(0, __float_as_int(v), 0x4E, 0xF, 0xF, true));
  v += __int_as_float(__builtin_amdgcn_update_dpp(0, __float_as_int(v), 0x141, 0xF, 0xF, true));
  v += __int_as_float(__builtin_amdgcn_update_dpp(0, __float_as_int(v), 0x140, 0xF, 0xF, true));
  return v;
}

// linear upper-triangle tile id -> (by, bx), bx >= by
__device__ __forceinline__ void decode_tile(int t, int& by, int& bx) {
  int y = (int)((2.0 * MT + 1.0 -
                 __builtin_sqrt((2.0 * MT + 1.0) * (2.0 * MT + 1.0) - 8.0 * t)) * 0.5);
  while (y * MT - y * (y - 1) / 2 > t) --y;
  while ((y + 1) * MT - (y + 1) * y / 2 <= t) ++y;
  by = y;
  bx = y + (t - (y * MT - y * (y - 1) / 2));
}

// --- Kernel 1: fp8 cast into INTERLEAVED-K layout + row norms ---------------
// Global row layout: slab s (K=128) at bytes [s*128, +128); within a slab,
// chunk u (0..7, 16 B) = k-bytes [u*8,+8) (low half) ++ [64+u*8,+8) (high).
// One b128 LDS read of chunk u = j*4+quad then yields the MFMA fragment for
// k-steps j (low 8 B) and j+2 (high 8 B) of that slab.
__global__ __launch_bounds__(256) void prep_kernel(
    const float* __restrict__ emb, unsigned char* __restrict__ Efp8,
    float* __restrict__ sq, Ctrl* __restrict__ ctrl)
{
  const int lane = threadIdx.x & 63;
  const int wave = threadIdx.x >> 6;
  if (blockIdx.x == 0 && threadIdx.x == 0) {
    ctrl->Ssum = 0.0;
    ctrl->c1 = 0;
    ctrl->c2 = 0;
  }
  // lane l handles k = 4l..4l+3 -> dword index in interleaved layout:
  const int dst = (lane >> 5) * 32 + ((lane & 15) >> 1) * 4 +
                  (((lane >> 4) & 1) << 1) + (lane & 1);
  #pragma unroll
  for (int i = 0; i < 4; ++i) {
    const int row = blockIdx.x * 16 + i * 4 + wave;
    const float4 x = *(const float4*)(emb + (size_t)row * E + lane * 4);
    int pk = __builtin_amdgcn_cvt_pk_fp8_f32(x.x, x.y, 0, false);
    pk = __builtin_amdgcn_cvt_pk_fp8_f32(x.z, x.w, pk, true);
    ((unsigned int*)(Efp8 + (size_t)row * EB))[dst] = (unsigned int)pk;
    float s = x.x * x.x + x.y * x.y + x.z * x.z + x.w * x.w;
    #pragma unroll
    for (int off = 32; off > 0; off >>= 1) s += __shfl_down(s, off, 64);
    if (lane == 0) sq[row] = s;
  }
}

// --- Kernel 2: fp8 MFMA Gram (128-tile, triangular) + fused fin tail --------
// Store-only epilogue into doubled slices: tile (by,bx) writes row-sums to
// slice 2*bx+waveN (segment by) and col-sums to slice 2*by+waveM (segment bx).
// Every (slice, segment) element is written exactly once -> plain stores, no
// atomics, no init. Frag reads are b128 with R4's measured-zero-conflict
// pattern. LDS = 32 KB -> 5 blocks/CU. Last FINB tickets run the reduction.
__global__ __launch_bounds__(256, 5) void gram_kernel(
    const unsigned char* __restrict__ Efp8, const float* __restrict__ sq,
    const int* __restrict__ labels, float* __restrict__ numpart,
    float* __restrict__ denpart, Ctrl* __restrict__ ctrl,
    float* __restrict__ out)
{
  __shared__ alignas(16) unsigned char As[BT * 128];  // 16 KB (one K=128 slab)
  __shared__ alignas(16) unsigned char Bs[BT * 128];  // 16 KB

  int by, bx;
  decode_tile(blockIdx.x, by, bx);
  const bool diag = (bx == by);

  const int tid = threadIdx.x;
  const int lane = tid & 63;
  const int wave = tid >> 6;
  const int waveM = wave >> 1;
  const int waveN = wave & 1;
  const int quad = lane >> 4;
  const int l16 = lane & 15;

  const int rowBase = by * BT;
  const int colBase = bx * BT;
  const char* gbase = (const char*)Efp8;

  floatx4 acc[4][4];
  #pragma unroll
  for (int i = 0; i < 4; ++i)
    #pragma unroll
    for (int j = 0; j < 4; ++j)
      acc[i][j] = (floatx4){0.f, 0.f, 0.f, 0.f};

  // stage one K=128 slab (16 KB) = 4 rounds x 256 threads x 16 B.
  // LDS chunk (r, c) <- global chunk u = c^(r&7) of slab s (XOR swizzle).
  #define STAGE(buf, rb, s)                                                  \
    _Pragma("unroll")                                                        \
    for (int it = 0; it < 4; ++it) {                                         \
      const int c = it * 256 + tid;                                          \
      const int r = c >> 3;                                                  \
      const int u = (c & 7) ^ (r & 7);                                       \
      const char* g = gbase + (size_t)((rb) + r) * EB + (s) * 128 + u * 16;  \
      __builtin_amdgcn_global_load_lds((gptr_t)g, (sptr_t)((buf) + c * 16),  \
                                       16, 0, 0);                            \
    }

  STAGE(As, rowBase, 0)
  if (!diag) STAGE(Bs, colBase, 0)

  for (int s = 0; s < 2; ++s) {
    __syncthreads();  // vmcnt(0) drain: slab staged
    const unsigned char* Bsrc = diag ? As : Bs;
    #pragma unroll
    for (int j = 0; j < 2; ++j) {
      longx2 afj[4], bfj[4];
      #pragma unroll
      for (int mi = 0; mi < 4; ++mi) {
        const int r = waveM * 64 + mi * 16 + l16;
        afj[mi] = *(const longx2*)((const char*)As + r * 128 +
                                   (((j * 4 + quad) ^ (r & 7)) << 4));
      }
      #pragma unroll
      for (int ni = 0; ni < 4; ++ni) {
        const int r = waveN * 64 + ni * 16 + l16;
        bfj[ni] = *(const longx2*)((const char*)Bsrc + r * 128 +
                                   (((j * 4 + quad) ^ (r & 7)) << 4));
      }
      #pragma unroll
      for (int h = 0; h < 2; ++h)  // low 8 B = step j, high 8 B = step j+2
        #pragma unroll
        for (int mi = 0; mi < 4; ++mi)
          #pragma unroll
          for (int ni = 0; ni < 4; ++ni)
            acc[mi][ni] = __builtin_amdgcn_mfma_f32_16x16x32_fp8_fp8(
                afj[mi][h], bfj[ni][h], acc[mi][ni], 0, 0, 0);
    }
    __syncthreads();  // done reading this slab
    if (s == 0) {
      STAGE(As, rowBase, 1)
      if (!diag) STAGE(Bs, colBase, 1)
    }
  }

  // ---- epilogue: registers + DPP + plain unique-writer stores --------------
  float sqc[4];
  int lc[4], cg[4];
  #pragma unroll
  for (int ni = 0; ni < 4; ++ni) {
    const int col = colBase + waveN * 64 + ni * 16 + l16;
    sqc[ni] = sq[col];
    lc[ni] = labels[col];
    cg[ni] = col;
  }

  float ncp[4] = {0.f, 0.f, 0.f, 0.f};
  float dcp[4] = {0.f, 0.f, 0.f, 0.f};

  #pragma unroll
  for (int mi = 0; mi < 4; ++mi) {
    const int rbase = rowBase + waveM * 64 + mi * 16 + quad * 4;
    const float4 sqr4 = *(const float4*)(sq + rbase);
    const int4 lr4 = *(const int4*)(labels + rbase);
    const float sqr[4] = {sqr4.x, sqr4.y, sqr4.z, sqr4.w};
    const int lr[4] = {lr4.x, lr4.y, lr4.z, lr4.w};
    float npv[4], dpv[4];
    #pragma unroll
    for (int r = 0; r < 4; ++r) {
      float np = 0.f, dp = 0.f;
      #pragma unroll
      for (int ni = 0; ni < 4; ++ni) {
        float d2 = fmaxf(fmaf(-2.f, acc[mi][ni][r], sqr[r] + sqc[ni]), EPS);
        if (diag && (rbase + r == cg[ni])) d2 = EPS;  // exact diagonal
        float d = __builtin_amdgcn_sqrtf(d2);
        float rc = __builtin_amdgcn_rcpf(d + MARGIN);
        const bool same = (lr[r] == lc[ni]);
        const float dsel = same ? d : 0.f;
        const float rsel = same ? 0.f : rc;
        np += dsel; dp += rsel;
        ncp[ni] += dsel; dcp[ni] += rsel;
      }
      npv[r] = dpp_sum16(np);
      dpv[r] = dpp_sum16(dp);
    }
    const float seln = (l16 & 2) ? ((l16 & 1) ? npv[3] : npv[2])
                                 : ((l16 & 1) ? npv[1] : npv[0]);
    const float seld = (l16 & 2) ? ((l16 & 1) ? dpv[3] : dpv[2])
                                 : ((l16 & 1) ? dpv[1] : dpv[0]);
    if ((l16 >> 2) == quad) {  // one lane per row; per-waveN slice
      const int row = rowBase + waveM * 64 + mi * 16 + l16;
      numpart[(size_t)(2 * bx + waveN) * N + row] = seln;
      denpart[(size_t)(2 * bx + waveN) * N + row] = seld;
    }
  }

  if (!diag) {  // col partials: quad-reduce in-wave, per-waveM slice
    #pragma unroll
    for (int ni = 0; ni < 4; ++ni) {
      float n2 = ncp[ni], d2 = dcp[ni];
      n2 += __shfl_xor(n2, 16, 64); d2 += __shfl_xor(d2, 16, 64);
      n2 += __shfl_xor(n2, 32, 64); d2 += __shfl_xor(d2, 32, 64);
      if (quad == 0) {
        const int col = colBase + waveN * 64 + ni * 16 + l16;
        numpart[(size_t)(2 * by + waveM) * N + col] = n2;
        denpart[(size_t)(2 * by + waveM) * N + col] = d2;
      }
    }
  }

  // ---- ticket tail: last FINB tickets do the reduction ---------------------
  __threadfence();  // partials visible at agent scope before release ticket
  __syncthreads();
  int* shTicket = (int*)(As + 128);  // As free now
  if (tid == 0)
    *shTicket = __hip_atomic_fetch_add(&ctrl->c1, 1, __ATOMIC_ACQ_REL,
                                       __HIP_MEMORY_SCOPE_AGENT);
  __syncthreads();
  const int ticket = *shTicket;
  if (ticket < NTILES - FINB) return;
  const int fb = ticket - (NTILES - FINB);  // 0..31

  if (tid == 0) {
    while (__hip_atomic_load(&ctrl->c1, __ATOMIC_ACQUIRE,
                             __HIP_MEMORY_SCOPE_AGENT) < NTILES)
      __builtin_amdgcn_s_sleep(1);
  }
  __syncthreads();

  double* shd = (double*)As;
  int* lastflag = (int*)(As + 64);
  int* hist = (int*)(As + 256);

  const int a = fb * 256 + tid;
  float np = 0.f, dp = 0.f;
  #pragma unroll 4
  for (int k = 0; k < SL; ++k) {
    np += numpart[(size_t)k * N + a];
    dp += denpart[(size_t)k * N + a];
  }
  double s = (double)np * (double)dp;
  #pragma unroll
  for (int off = 32; off > 0; off >>= 1) s += __shfl_down(s, off, 64);
  if (lane == 0) shd[wave] = s;
  __syncthreads();
  if (tid == 0) {
    unsafeAtomicAdd(&ctrl->Ssum, shd[0] + shd[1] + shd[2] + shd[3]);
    __threadfence();
    const int prev = __hip_atomic_fetch_add(&ctrl->c2, 1, __ATOMIC_ACQ_REL,
                                            __HIP_MEMORY_SCOPE_AGENT);
    *lastflag = (prev == FINB - 1) ? 1 : 0;
  }
  __syncthreads();

  if (*lastflag) {
    if (tid < NUM_CLASSES) hist[tid] = 0;
    __syncthreads();
    for (int i = tid; i < N; i += 256) atomicAdd(&hist[labels[i]], 1);
    __syncthreads();
    double m = 0.0;
    if (tid < NUM_CLASSES) {
      const double cc = (double)hist[tid];
      m = cc * cc * (double)(N - cc);
    }
    #pragma unroll
    for (int off = 32; off > 0; off >>= 1) m += __shfl_down(m, off, 64);
    __syncthreads();
    if (lane == 0) shd[wave] = m;
    __syncthreads();
    if (tid == 0) {
      const double M = shd[0] + shd[1] + shd[2] + shd[3];
      const double S = __hip_atomic_load(&ctrl->Ssum, __ATOMIC_ACQUIRE,
                                         __HIP_MEMORY_SCOPE_AGENT);
      out[0] = (float)(S / M);
    }
  }
}

extern "C" void kernel_launch(void* const* d_in, const int* in_sizes, int n_in,
                              void* d_out, int out_size, void* d_ws, size_t ws_size,
                              hipStream_t stream) {
  const float* emb = (const float*)d_in[0];
  const int* labels = (const int*)d_in[1];
  float* out = (float*)d_out;

  // ws: Efp8[2MB] | sq[32KB] | numpart[4MB] | denpart[4MB] | Ctrl  (~10 MB)
  char* w = (char*)d_ws;
  unsigned char* Efp8 = (unsigned char*)w;
  float* sq = (float*)(w + (size_t)N * EB);
  float* numpart = sq + N;
  float* denpart = numpart + (size_t)SL * N;
  Ctrl* ctrl = (Ctrl*)(denpart + (size_t)SL * N);

  prep_kernel<<<N / 16, 256, 0, stream>>>(emb, Efp8, sq, ctrl);
  gram_kernel<<<NTILES, 256, 0, stream>>>(Efp8, sq, labels, numpart, denpart,
                                          ctrl, out);
}

// Round 10
// 337.828 us; speedup vs baseline: 1.4506x; 1.4506x over previous
//
#include <hip/hip_runtime.h>
#include <hip/hip_bf16.h>
#include <stdint.h>

#define N 8192
#define E 256
#define NUM_CLASSES 100
#define MARGIN 0.1f
#define EPS 1e-4f

#define BT 128                      // Gram tile dim
#define MT (N / BT)                 // 64 tile-rows
#define NTILES (MT * (MT + 1) / 2)  // 2080 upper-tri tiles
#define SL (2 * MT)                 // 128 partial slices (2 per tile index)
#define EB 256                      // fp8 row = 256 B
#define FINB 32                     // finisher blocks (ticket tail)

typedef __attribute__((ext_vector_type(4))) float floatx4;
typedef __attribute__((ext_vector_type(2))) long longx2;
typedef const __attribute__((address_space(1))) void* gptr_t;
typedef __attribute__((address_space(3))) void* sptr_t;

struct Ctrl { double Ssum; int c1, c2; };  // zeroed by prep block 0

// 16-lane butterfly sum on the VALU via DPP (no LDS-pipe usage).
__device__ __forceinline__ float dpp_sum16(float v) {
  v += __int_as_float(__builtin_amdgcn_update_dpp(0, __float_as_int(v), 0xB1, 0xF, 0xF, true));
  v += __int_as_float(__builtin_amdgcn_update_dpp(0, __float_as_int(v), 0x4E, 0xF, 0xF, true));
  v += __int_as_float(__builtin_amdgcn_update_dpp(0, __float_as_int(v), 0x141, 0xF, 0xF, true));
  v += __int_as_float(__builtin_amdgcn_update_dpp(0, __float_as_int(v), 0x140, 0xF, 0xF, true));
  return v;
}

// linear upper-triangle tile id -> (by, bx), bx >= by
__device__ __forceinline__ void decode_tile(int t, int& by, int& bx) {
  int y = (int)((2.0 * MT + 1.0 -
                 __builtin_sqrt((2.0 * MT + 1.0) * (2.0 * MT + 1.0) - 8.0 * t)) * 0.5);
  while (y * MT - y * (y - 1) / 2 > t) --y;
  while ((y + 1) * MT - (y + 1) * y / 2 <= t) ++y;
  by = y;
  bx = y + (t - (y * MT - y * (y - 1) / 2));
}

// --- Kernel 1: fp8 cast into INTERLEAVED-K layout + row norms ---------------
// Global row layout: slab s (K=128) at bytes [s*128, +128); within a slab,
// chunk u (0..7, 16 B) = k-bytes [u*8,+8) (low half) ++ [64+u*8,+8) (high).
// One b128 LDS read of chunk u = j*4+quad then yields the MFMA fragment for
// k-steps j (low 8 B) and j+2 (high 8 B) of that slab.
__global__ __launch_bounds__(256) void prep_kernel(
    const float* __restrict__ emb, unsigned char* __restrict__ Efp8,
    float* __restrict__ sq, Ctrl* __restrict__ ctrl)
{
  const int lane = threadIdx.x & 63;
  const int wave = threadIdx.x >> 6;
  if (blockIdx.x == 0 && threadIdx.x == 0) {
    ctrl->Ssum = 0.0;
    ctrl->c1 = 0;
    ctrl->c2 = 0;
  }
  // lane l handles k = 4l..4l+3 -> dword index in interleaved layout:
  const int dst = (lane >> 5) * 32 + ((lane & 15) >> 1) * 4 +
                  (((lane >> 4) & 1) << 1) + (lane & 1);
  #pragma unroll
  for (int i = 0; i < 4; ++i) {
    const int row = blockIdx.x * 16 + i * 4 + wave;
    const float4 x = *(const float4*)(emb + (size_t)row * E + lane * 4);
    int pk = __builtin_amdgcn_cvt_pk_fp8_f32(x.x, x.y, 0, false);
    pk = __builtin_amdgcn_cvt_pk_fp8_f32(x.z, x.w, pk, true);
    ((unsigned int*)(Efp8 + (size_t)row * EB))[dst] = (unsigned int)pk;
    float s = x.x * x.x + x.y * x.y + x.z * x.z + x.w * x.w;
    #pragma unroll
    for (int off = 32; off > 0; off >>= 1) s += __shfl_down(s, off, 64);
    if (lane == 0) sq[row] = s;
  }
}

// --- Kernel 2: fp8 MFMA Gram (128-tile, triangular) + fused fin tail --------
// Store-only epilogue into doubled slices: tile (by,bx) writes row-sums to
// slice 2*bx+waveN (segment by) and col-sums to slice 2*by+waveM (segment bx).
// Every (slice, segment) element is written exactly once -> plain stores, no
// atomics, no init. Frag reads are b128, measured-zero-conflict (R9: 658).
// NOTE __launch_bounds__ 2nd arg is MIN WAVES PER SIMD: 5 capped VGPRs at 96
// and spilled acc to scratch (R9: 363 MB scratch traffic, 8x regression).
// (256,2) = 256-VGPR cap, no spill; occupancy settles at ~3 blocks/CU.
__global__ __launch_bounds__(256, 2) void gram_kernel(
    const unsigned char* __restrict__ Efp8, const float* __restrict__ sq,
    const int* __restrict__ labels, float* __restrict__ numpart,
    float* __restrict__ denpart, Ctrl* __restrict__ ctrl,
    float* __restrict__ out)
{
  __shared__ alignas(16) unsigned char As[BT * 128];  // 16 KB (one K=128 slab)
  __shared__ alignas(16) unsigned char Bs[BT * 128];  // 16 KB

  int by, bx;
  decode_tile(blockIdx.x, by, bx);
  const bool diag = (bx == by);

  const int tid = threadIdx.x;
  const int lane = tid & 63;
  const int wave = tid >> 6;
  const int waveM = wave >> 1;
  const int waveN = wave & 1;
  const int quad = lane >> 4;
  const int l16 = lane & 15;

  const int rowBase = by * BT;
  const int colBase = bx * BT;
  const char* gbase = (const char*)Efp8;

  floatx4 acc[4][4];
  #pragma unroll
  for (int i = 0; i < 4; ++i)
    #pragma unroll
    for (int j = 0; j < 4; ++j)
      acc[i][j] = (floatx4){0.f, 0.f, 0.f, 0.f};

  // stage one K=128 slab (16 KB) = 4 rounds x 256 threads x 16 B.
  // LDS chunk (r, c) <- global chunk u = c^(r&7) of slab s (XOR swizzle).
  #define STAGE(buf, rb, s)                                                  \
    _Pragma("unroll")                                                        \
    for (int it = 0; it < 4; ++it) {                                         \
      const int c = it * 256 + tid;                                          \
      const int r = c >> 3;                                                  \
      const int u = (c & 7) ^ (r & 7);                                       \
      const char* g = gbase + (size_t)((rb) + r) * EB + (s) * 128 + u * 16;  \
      __builtin_amdgcn_global_load_lds((gptr_t)g, (sptr_t)((buf) + c * 16),  \
                                       16, 0, 0);                            \
    }

  STAGE(As, rowBase, 0)
  if (!diag) STAGE(Bs, colBase, 0)

  for (int s = 0; s < 2; ++s) {
    __syncthreads();  // vmcnt(0) drain: slab staged
    const unsigned char* Bsrc = diag ? As : Bs;
    #pragma unroll
    for (int j = 0; j < 2; ++j) {
      longx2 afj[4], bfj[4];
      #pragma unroll
      for (int mi = 0; mi < 4; ++mi) {
        const int r = waveM * 64 + mi * 16 + l16;
        afj[mi] = *(const longx2*)((const char*)As + r * 128 +
                                   (((j * 4 + quad) ^ (r & 7)) << 4));
      }
      #pragma unroll
      for (int ni = 0; ni < 4; ++ni) {
        const int r = waveN * 64 + ni * 16 + l16;
        bfj[ni] = *(const longx2*)((const char*)Bsrc + r * 128 +
                                   (((j * 4 + quad) ^ (r & 7)) << 4));
      }
      #pragma unroll
      for (int h = 0; h < 2; ++h)  // low 8 B = step j, high 8 B = step j+2
        #pragma unroll
        for (int mi = 0; mi < 4; ++mi)
          #pragma unroll
          for (int ni = 0; ni < 4; ++ni)
            acc[mi][ni] = __builtin_amdgcn_mfma_f32_16x16x32_fp8_fp8(
                afj[mi][h], bfj[ni][h], acc[mi][ni], 0, 0, 0);
    }
    __syncthreads();  // done reading this slab
    if (s == 0) {
      STAGE(As, rowBase, 1)
      if (!diag) STAGE(Bs, colBase, 1)
    }
  }

  // ---- epilogue: registers + DPP + plain unique-writer stores --------------
  float sqc[4];
  int lc[4], cg[4];
  #pragma unroll
  for (int ni = 0; ni < 4; ++ni) {
    const int col = colBase + waveN * 64 + ni * 16 + l16;
    sqc[ni] = sq[col];
    lc[ni] = labels[col];
    cg[ni] = col;
  }

  float ncp[4] = {0.f, 0.f, 0.f, 0.f};
  float dcp[4] = {0.f, 0.f, 0.f, 0.f};

  #pragma unroll
  for (int mi = 0; mi < 4; ++mi) {
    const int rbase = rowBase + waveM * 64 + mi * 16 + quad * 4;
    const float4 sqr4 = *(const float4*)(sq + rbase);
    const int4 lr4 = *(const int4*)(labels + rbase);
    const float sqr[4] = {sqr4.x, sqr4.y, sqr4.z, sqr4.w};
    const int lr[4] = {lr4.x, lr4.y, lr4.z, lr4.w};
    float npv[4], dpv[4];
    #pragma unroll
    for (int r = 0; r < 4; ++r) {
      float np = 0.f, dp = 0.f;
      #pragma unroll
      for (int ni = 0; ni < 4; ++ni) {
        float d2 = fmaxf(fmaf(-2.f, acc[mi][ni][r], sqr[r] + sqc[ni]), EPS);
        if (diag && (rbase + r == cg[ni])) d2 = EPS;  // exact diagonal
        float d = __builtin_amdgcn_sqrtf(d2);
        float rc = __builtin_amdgcn_rcpf(d + MARGIN);
        const bool same = (lr[r] == lc[ni]);
        const float dsel = same ? d : 0.f;
        const float rsel = same ? 0.f : rc;
        np += dsel; dp += rsel;
        ncp[ni] += dsel; dcp[ni] += rsel;
      }
      npv[r] = dpp_sum16(np);
      dpv[r] = dpp_sum16(dp);
    }
    const float seln = (l16 & 2) ? ((l16 & 1) ? npv[3] : npv[2])
                                 : ((l16 & 1) ? npv[1] : npv[0]);
    const float seld = (l16 & 2) ? ((l16 & 1) ? dpv[3] : dpv[2])
                                 : ((l16 & 1) ? dpv[1] : dpv[0]);
    if ((l16 >> 2) == quad) {  // one lane per row; per-waveN slice
      const int row = rowBase + waveM * 64 + mi * 16 + l16;
      numpart[(size_t)(2 * bx + waveN) * N + row] = seln;
      denpart[(size_t)(2 * bx + waveN) * N + row] = seld;
    }
  }

  if (!diag) {  // col partials: quad-reduce in-wave, per-waveM slice
    #pragma unroll
    for (int ni = 0; ni < 4; ++ni) {
      float n2 = ncp[ni], d2 = dcp[ni];
      n2 += __shfl_xor(n2, 16, 64); d2 += __shfl_xor(d2, 16, 64);
      n2 += __shfl_xor(n2, 32, 64); d2 += __shfl_xor(d2, 32, 64);
      if (quad == 0) {
        const int col = colBase + waveN * 64 + ni * 16 + l16;
        numpart[(size_t)(2 * by + waveM) * N + col] = n2;
        denpart[(size_t)(2 * by + waveM) * N + col] = d2;
      }
    }
  }

  // ---- ticket tail: last FINB tickets do the reduction ---------------------
  __threadfence();  // partials visible at agent scope before release ticket
  __syncthreads();
  int* shTicket = (int*)(As + 128);  // As free now
  if (tid == 0)
    *shTicket = __hip_atomic_fetch_add(&ctrl->c1, 1, __ATOMIC_ACQ_REL,
                                       __HIP_MEMORY_SCOPE_AGENT);
  __syncthreads();
  const int ticket = *shTicket;
  if (ticket < NTILES - FINB) return;
  const int fb = ticket - (NTILES - FINB);  // 0..31

  if (tid == 0) {
    while (__hip_atomic_load(&ctrl->c1, __ATOMIC_ACQUIRE,
                             __HIP_MEMORY_SCOPE_AGENT) < NTILES)
      __builtin_amdgcn_s_sleep(1);
  }
  __syncthreads();

  double* shd = (double*)As;
  int* lastflag = (int*)(As + 64);
  int* hist = (int*)(As + 256);

  const int a = fb * 256 + tid;
  float np = 0.f, dp = 0.f;
  #pragma unroll 4
  for (int k = 0; k < SL; ++k) {
    np += numpart[(size_t)k * N + a];
    dp += denpart[(size_t)k * N + a];
  }
  double s = (double)np * (double)dp;
  #pragma unroll
  for (int off = 32; off > 0; off >>= 1) s += __shfl_down(s, off, 64);
  if (lane == 0) shd[wave] = s;
  __syncthreads();
  if (tid == 0) {
    unsafeAtomicAdd(&ctrl->Ssum, shd[0] + shd[1] + shd[2] + shd[3]);
    __threadfence();
    const int prev = __hip_atomic_fetch_add(&ctrl->c2, 1, __ATOMIC_ACQ_REL,
                                            __HIP_MEMORY_SCOPE_AGENT);
    *lastflag = (prev == FINB - 1) ? 1 : 0;
  }
  __syncthreads();

  if (*lastflag) {
    if (tid < NUM_CLASSES) hist[tid] = 0;
    __syncthreads();
    for (int i = tid; i < N; i += 256) atomicAdd(&hist[labels[i]], 1);
    __syncthreads();
    double m = 0.0;
    if (tid < NUM_CLASSES) {
      const double cc = (double)hist[tid];
      m = cc * cc * (double)(N - cc);
    }
    #pragma unroll
    for (int off = 32; off > 0; off >>= 1) m += __shfl_down(m, off, 64);
    __syncthreads();
    if (lane == 0) shd[wave] = m;
    __syncthreads();
    if (tid == 0) {
      const double M = shd[0] + shd[1] + shd[2] + shd[3];
      const double S = __hip_atomic_load(&ctrl->Ssum, __ATOMIC_ACQUIRE,
                                         __HIP_MEMORY_SCOPE_AGENT);
      out[0] = (float)(S / M);
    }
  }
}

extern "C" void kernel_launch(void* const* d_in, const int* in_sizes, int n_in,
                              void* d_out, int out_size, void* d_ws, size_t ws_size,
                              hipStream_t stream) {
  const float* emb = (const float*)d_in[0];
  const int* labels = (const int*)d_in[1];
  float* out = (float*)d_out;

  // ws: Efp8[2MB] | sq[32KB] | numpart[4MB] | denpart[4MB] | Ctrl  (~10 MB)
  char* w = (char*)d_ws;
  unsigned char* Efp8 = (unsigned char*)w;
  float* sq = (float*)(w + (size_t)N * EB);
  float* numpart = sq + N;
  float* denpart = numpart + (size_t)SL * N;
  Ctrl* ctrl = (Ctrl*)(denpart + (size_t)SL * N);

  prep_kernel<<<N / 16, 256, 0, stream>>>(emb, Efp8, sq, ctrl);
  gram_kernel<<<NTILES, 256, 0, stream>>>(Efp8, sq, labels, numpart, denpart,
                                          ctrl, out);
}

// Round 11
// 107.526 us; speedup vs baseline: 4.5577x; 3.1418x over previous
//
#include <hip/hip_runtime.h>
#include <hip/hip_bf16.h>
#include <stdint.h>

#define N 8192
#define E 256
#define NUM_CLASSES 100
#define MARGIN 0.1f
#define EPS 1e-4f

#define BT 128                      // Gram tile dim
#define MT (N / BT)                 // 64 tile-rows
#define NTILES (MT * (MT + 1) / 2)  // 2080 upper-tri tiles
#define SL (2 * MT)                 // 128 partial slices (2 per tile index)
#define EB 256                      // fp8 row = 256 B
#define FINB 32                     // fin blocks

typedef __attribute__((ext_vector_type(4))) float floatx4;
typedef __attribute__((ext_vector_type(2))) long longx2;
typedef const __attribute__((address_space(1))) void* gptr_t;
typedef __attribute__((address_space(3))) void* sptr_t;

struct Ctrl { double Ssum; int c2; };  // zeroed by prep block 0

// 16-lane butterfly sum on the VALU via DPP (no LDS-pipe usage).
__device__ __forceinline__ float dpp_sum16(float v) {
  v += __int_as_float(__builtin_amdgcn_update_dpp(0, __float_as_int(v), 0xB1, 0xF, 0xF, true));
  v += __int_as_float(__builtin_amdgcn_update_dpp(0, __float_as_int(v), 0x4E, 0xF, 0xF, true));
  v += __int_as_float(__builtin_amdgcn_update_dpp(0, __float_as_int(v), 0x141, 0xF, 0xF, true));
  v += __int_as_float(__builtin_amdgcn_update_dpp(0, __float_as_int(v), 0x140, 0xF, 0xF, true));
  return v;
}

// linear upper-triangle tile id -> (by, bx), bx >= by
__device__ __forceinline__ void decode_tile(int t, int& by, int& bx) {
  int y = (int)((2.0 * MT + 1.0 -
                 __builtin_sqrt((2.0 * MT + 1.0) * (2.0 * MT + 1.0) - 8.0 * t)) * 0.5);
  while (y * MT - y * (y - 1) / 2 > t) --y;
  while ((y + 1) * MT - (y + 1) * y / 2 <= t) ++y;
  by = y;
  bx = y + (t - (y * MT - y * (y - 1) / 2));
}

// --- Kernel 1: fp8 cast into INTERLEAVED-K layout + row norms ---------------
// Row layout: slab s (K=128) at [s*128,+128); chunk u (16 B) = k-bytes
// [u*8,+8) ++ [64+u*8,+8). One b128 read of chunk u=j*4+quad yields MFMA
// fragments for k-steps j (low 8 B) and j+2 (high 8 B).
// Writes are CONTIGUOUS (lane l writes dword l); the permutation is applied
// on the read side instead (R10's scattered 4-B stores inverted).
__global__ __launch_bounds__(256) void prep_kernel(
    const float* __restrict__ emb, unsigned char* __restrict__ Efp8,
    float* __restrict__ sq, Ctrl* __restrict__ ctrl)
{
  const int lane = threadIdx.x & 63;
  const int wave = threadIdx.x >> 6;
  if (blockIdx.x == 0 && threadIdx.x == 0) {
    ctrl->Ssum = 0.0;
    ctrl->c2 = 0;
  }
  // dword d holds k-range of source lane: src = inverse permutation of
  // dst = (g5)<<5 | g[3:1]<<2 | g4<<1 | g0  (verified bijection)
  const int d = lane;
  const int src = (d & 32) | (((d >> 1) & 1) << 4) | (((d >> 2) & 7) << 1) | (d & 1);
  #pragma unroll
  for (int i = 0; i < 4; ++i) {
    const int row = blockIdx.x * 16 + i * 4 + wave;
    const float4 x = *(const float4*)(emb + (size_t)row * E + src * 4);
    int pk = __builtin_amdgcn_cvt_pk_fp8_f32(x.x, x.y, 0, false);
    pk = __builtin_amdgcn_cvt_pk_fp8_f32(x.z, x.w, pk, true);
    ((unsigned int*)(Efp8 + (size_t)row * EB))[d] = (unsigned int)pk;
    float s = x.x * x.x + x.y * x.y + x.z * x.z + x.w * x.w;
    #pragma unroll
    for (int off = 32; off > 0; off >>= 1) s += __shfl_down(s, off, 64);
    if (lane == 0) sq[row] = s;
  }
}

// --- Kernel 2: fp8 MFMA Gram (128-tile, triangular), NO fences/atomics ------
// Store-only epilogue into doubled slices: tile (by,bx) writes row-sums to
// slice 2*bx+waveN (segment by), col-sums to slice 2*by+waveM (segment bx).
// Every (slice,segment) written exactly once -> plain stores, no init.
// R10 lesson: device-scope threadfence + spin per block poisoned the TCC
// (285us for 58us of work). Grid-wide hand-off now at dispatch boundary.
// R9 lesson: __launch_bounds__ 2nd arg is MIN WAVES PER SIMD (5 => 96-VGPR
// cap => acc spilled to scratch, 363 MB traffic). Keep (256,2).
__global__ __launch_bounds__(256, 2) void gram_kernel(
    const unsigned char* __restrict__ Efp8, const float* __restrict__ sq,
    const int* __restrict__ labels, float* __restrict__ numpart,
    float* __restrict__ denpart)
{
  __shared__ alignas(16) unsigned char As[BT * 128];  // 16 KB (one K=128 slab)
  __shared__ alignas(16) unsigned char Bs[BT * 128];  // 16 KB

  int by, bx;
  decode_tile(blockIdx.x, by, bx);
  const bool diag = (bx == by);

  const int tid = threadIdx.x;
  const int lane = tid & 63;
  const int wave = tid >> 6;
  const int waveM = wave >> 1;
  const int waveN = wave & 1;
  const int quad = lane >> 4;
  const int l16 = lane & 15;

  const int rowBase = by * BT;
  const int colBase = bx * BT;
  const char* gbase = (const char*)Efp8;

  floatx4 acc[4][4];
  #pragma unroll
  for (int i = 0; i < 4; ++i)
    #pragma unroll
    for (int j = 0; j < 4; ++j)
      acc[i][j] = (floatx4){0.f, 0.f, 0.f, 0.f};

  // stage one K=128 slab (16 KB) = 4 rounds x 256 threads x 16 B.
  // LDS chunk (r, c) <- global chunk u = c^(r&7) of slab s (XOR swizzle;
  // measured-zero-conflict with the b128 frag reads below, R9/R10: 658).
  #define STAGE(buf, rb, s)                                                  \
    _Pragma("unroll")                                                        \
    for (int it = 0; it < 4; ++it) {                                         \
      const int c = it * 256 + tid;                                          \
      const int r = c >> 3;                                                  \
      const int u = (c & 7) ^ (r & 7);                                       \
      const char* g = gbase + (size_t)((rb) + r) * EB + (s) * 128 + u * 16;  \
      __builtin_amdgcn_global_load_lds((gptr_t)g, (sptr_t)((buf) + c * 16),  \
                                       16, 0, 0);                            \
    }

  STAGE(As, rowBase, 0)
  if (!diag) STAGE(Bs, colBase, 0)

  for (int s = 0; s < 2; ++s) {
    __syncthreads();  // vmcnt(0) drain: slab staged
    const unsigned char* Bsrc = diag ? As : Bs;
    #pragma unroll
    for (int j = 0; j < 2; ++j) {
      longx2 afj[4], bfj[4];
      #pragma unroll
      for (int mi = 0; mi < 4; ++mi) {
        const int r = waveM * 64 + mi * 16 + l16;
        afj[mi] = *(const longx2*)((const char*)As + r * 128 +
                                   (((j * 4 + quad) ^ (r & 7)) << 4));
      }
      #pragma unroll
      for (int ni = 0; ni < 4; ++ni) {
        const int r = waveN * 64 + ni * 16 + l16;
        bfj[ni] = *(const longx2*)((const char*)Bsrc + r * 128 +
                                   (((j * 4 + quad) ^ (r & 7)) << 4));
      }
      #pragma unroll
      for (int h = 0; h < 2; ++h)  // low 8 B = step j, high 8 B = step j+2
        #pragma unroll
        for (int mi = 0; mi < 4; ++mi)
          #pragma unroll
          for (int ni = 0; ni < 4; ++ni)
            acc[mi][ni] = __builtin_amdgcn_mfma_f32_16x16x32_fp8_fp8(
                afj[mi][h], bfj[ni][h], acc[mi][ni], 0, 0, 0);
    }
    __syncthreads();  // done reading this slab
    if (s == 0) {
      STAGE(As, rowBase, 1)
      if (!diag) STAGE(Bs, colBase, 1)
    }
  }

  // ---- epilogue: registers + DPP + plain unique-writer stores --------------
  float sqc[4];
  int lc[4], cg[4];
  #pragma unroll
  for (int ni = 0; ni < 4; ++ni) {
    const int col = colBase + waveN * 64 + ni * 16 + l16;
    sqc[ni] = sq[col];
    lc[ni] = labels[col];
    cg[ni] = col;
  }

  float ncp[4] = {0.f, 0.f, 0.f, 0.f};
  float dcp[4] = {0.f, 0.f, 0.f, 0.f};

  #pragma unroll
  for (int mi = 0; mi < 4; ++mi) {
    const int rbase = rowBase + waveM * 64 + mi * 16 + quad * 4;
    const float4 sqr4 = *(const float4*)(sq + rbase);
    const int4 lr4 = *(const int4*)(labels + rbase);
    const float sqr[4] = {sqr4.x, sqr4.y, sqr4.z, sqr4.w};
    const int lr[4] = {lr4.x, lr4.y, lr4.z, lr4.w};
    float npv[4], dpv[4];
    #pragma unroll
    for (int r = 0; r < 4; ++r) {
      float np = 0.f, dp = 0.f;
      #pragma unroll
      for (int ni = 0; ni < 4; ++ni) {
        float d2 = fmaxf(fmaf(-2.f, acc[mi][ni][r], sqr[r] + sqc[ni]), EPS);
        if (diag && (rbase + r == cg[ni])) d2 = EPS;  // exact diagonal
        float d = __builtin_amdgcn_sqrtf(d2);
        float rc = __builtin_amdgcn_rcpf(d + MARGIN);
        const bool same = (lr[r] == lc[ni]);
        const float dsel = same ? d : 0.f;
        const float rsel = same ? 0.f : rc;
        np += dsel; dp += rsel;
        ncp[ni] += dsel; dcp[ni] += rsel;
      }
      npv[r] = dpp_sum16(np);
      dpv[r] = dpp_sum16(dp);
    }
    const float seln = (l16 & 2) ? ((l16 & 1) ? npv[3] : npv[2])
                                 : ((l16 & 1) ? npv[1] : npv[0]);
    const float seld = (l16 & 2) ? ((l16 & 1) ? dpv[3] : dpv[2])
                                 : ((l16 & 1) ? dpv[1] : dpv[0]);
    if ((l16 >> 2) == quad) {  // one lane per row; per-waveN slice
      const int row = rowBase + waveM * 64 + mi * 16 + l16;
      numpart[(size_t)(2 * bx + waveN) * N + row] = seln;
      denpart[(size_t)(2 * bx + waveN) * N + row] = seld;
    }
  }

  if (!diag) {  // col partials: quad-reduce in-wave, per-waveM slice
    #pragma unroll
    for (int ni = 0; ni < 4; ++ni) {
      float n2 = ncp[ni], d2 = dcp[ni];
      n2 += __shfl_xor(n2, 16, 64); d2 += __shfl_xor(d2, 16, 64);
      n2 += __shfl_xor(n2, 32, 64); d2 += __shfl_xor(d2, 32, 64);
      if (quad == 0) {
        const int col = colBase + waveN * 64 + ni * 16 + l16;
        numpart[(size_t)(2 * by + waveM) * N + col] = n2;
        denpart[(size_t)(2 * by + waveM) * N + col] = d2;
      }
    }
  }
}

// --- Kernel 3: fold 128 slices, S-reduce, last block m_sum + divide ---------
__global__ __launch_bounds__(256) void fin_kernel(
    const float* __restrict__ numpart, const float* __restrict__ denpart,
    const int* __restrict__ labels, Ctrl* __restrict__ ctrl,
    float* __restrict__ out)
{
  __shared__ double sh[4];
  __shared__ int lastflag;
  __shared__ int hist[NUM_CLASSES];
  __shared__ double shm[4];

  const int tid = threadIdx.x;
  const int lane = tid & 63;
  const int wave = tid >> 6;
  const int a = blockIdx.x * 256 + tid;

  float np = 0.f, dp = 0.f;
  #pragma unroll 4
  for (int k = 0; k < SL; ++k) {
    np += numpart[(size_t)k * N + a];
    dp += denpart[(size_t)k * N + a];
  }
  double s = (double)np * (double)dp;
  #pragma unroll
  for (int off = 32; off > 0; off >>= 1) s += __shfl_down(s, off, 64);
  if (lane == 0) sh[wave] = s;
  __syncthreads();
  if (tid == 0) {
    unsafeAtomicAdd(&ctrl->Ssum, sh[0] + sh[1] + sh[2] + sh[3]);
    __threadfence();
    const int prev = __hip_atomic_fetch_add(&ctrl->c2, 1, __ATOMIC_ACQ_REL,
                                            __HIP_MEMORY_SCOPE_AGENT);
    lastflag = (prev == FINB - 1) ? 1 : 0;
  }
  __syncthreads();

  if (lastflag) {
    if (tid < NUM_CLASSES) hist[tid] = 0;
    __syncthreads();
    for (int i = tid; i < N; i += 256) atomicAdd(&hist[labels[i]], 1);
    __syncthreads();
    double m = 0.0;
    if (tid < NUM_CLASSES) {
      const double cc = (double)hist[tid];
      m = cc * cc * (double)(N - cc);
    }
    #pragma unroll
    for (int off = 32; off > 0; off >>= 1) m += __shfl_down(m, off, 64);
    if (lane == 0) shm[wave] = m;
    __syncthreads();
    if (tid == 0) {
      const double M = shm[0] + shm[1] + shm[2] + shm[3];
      const double S = __hip_atomic_load(&ctrl->Ssum, __ATOMIC_ACQUIRE,
                                         __HIP_MEMORY_SCOPE_AGENT);
      out[0] = (float)(S / M);
    }
  }
}

extern "C" void kernel_launch(void* const* d_in, const int* in_sizes, int n_in,
                              void* d_out, int out_size, void* d_ws, size_t ws_size,
                              hipStream_t stream) {
  const float* emb = (const float*)d_in[0];
  const int* labels = (const int*)d_in[1];
  float* out = (float*)d_out;

  // ws: Efp8[2MB] | sq[32KB] | numpart[4MB] | denpart[4MB] | Ctrl  (~10 MB)
  char* w = (char*)d_ws;
  unsigned char* Efp8 = (unsigned char*)w;
  float* sq = (float*)(w + (size_t)N * EB);
  float* numpart = sq + N;
  float* denpart = numpart + (size_t)SL * N;
  Ctrl* ctrl = (Ctrl*)(denpart + (size_t)SL * N);

  prep_kernel<<<N / 16, 256, 0, stream>>>(emb, Efp8, sq, ctrl);
  gram_kernel<<<NTILES, 256, 0, stream>>>(Efp8, sq, labels, numpart, denpart);
  fin_kernel<<<FINB, 256, 0, stream>>>(numpart, denpart, labels, ctrl, out);
}